// Round 2
// baseline (424061.865 us; speedup 1.0000x reference)
//
#include <hip/hip_runtime.h>

// =====================================================================
// AutoregressiveSubsetSampler — persistent cooperative kernel, MI355X.
// Round 6: store/gather exchange (NO fp64 atomics). Round-5 post-mortem:
// padded LLC atomics write-through to DRAM per-op (WRITE 3.4->12.9GB);
// dense atomics (R4) serialize 1024 RMW/line at the LLC. This round each
// WG STORES its partials to a private slot (coalesced, no RMW), and
// after the flag barrier every WG redundantly gathers + sums the 64
// partials per element with lane-coalesced pipelined loads in a fixed
// order (bitwise-identical across WGs). No zeroing, no parity buffers:
// the 2 barriers/step make single-buffer reuse WAR-safe.
//
// Per step t:
//  stage A: h1 slice local -> px/h partial STOREs -> arrive B1 ->
//           [m(t+1) prefetch] -> wait B1
//  stage B: gather64x2 px,h; fused ln1 -> x; f1 slice LOCAL (LDS);
//           logits slice -> sampling -> popc STOREs; pg partial STORE
//           -> arrive B2 -> [u(t+1) prefetch] -> wait B2
//  stage C: gather64 pg + counts (wave shuffle-reduce); fused ln2 -> g;
//           pick attempt; write row.
// All fp64 on the logit-critical chain (binary output: ~1e-13 margin).
// =====================================================================

typedef unsigned int u32;

#define NWG   64
#define NT    256
#define NSTEP 8192

// ---- relaxed agent-scope (LLC-direct, cache-bypassing) ops ----
__device__ __forceinline__ double gld(const double* p) {
  return __hip_atomic_load(p, __ATOMIC_RELAXED, __HIP_MEMORY_SCOPE_AGENT);
}
__device__ __forceinline__ void gst(double* p, double v) {
  __hip_atomic_store(p, v, __ATOMIC_RELAXED, __HIP_MEMORY_SCOPE_AGENT);
}
__device__ __forceinline__ u32 gldu(const u32* p) {
  return __hip_atomic_load(p, __ATOMIC_RELAXED, __HIP_MEMORY_SCOPE_AGENT);
}
__device__ __forceinline__ void gstu(u32* p, u32 v) {
  __hip_atomic_store(p, v, __ATOMIC_RELAXED, __HIP_MEMORY_SCOPE_AGENT);
}
__device__ __forceinline__ void gstf(float* p, float v) {
  __hip_atomic_store(p, v, __ATOMIC_RELAXED, __HIP_MEMORY_SCOPE_AGENT);
}

// ---- flag-array grid barrier, split into arrive / wait so independent
// prefetch loads can issue inside the poll window.
// __syncthreads in arrive drains each wave's vmcnt before lane 0 raises
// its flag -> all of the WG's global stores are LLC-acked first.
__device__ __forceinline__ void gbar_arrive(u32* flags, u32 e) {
  __syncthreads();
  if (threadIdx.x == 0) gstu(&flags[blockIdx.x], e);
}
__device__ __forceinline__ void gbar_wait(u32* flags, u32 e) {
  if (threadIdx.x < 64) {
    while (gldu(&flags[threadIdx.x]) < e) { }
  }
  asm volatile("" ::: "memory");
  __syncthreads();
}

// fused block-wide (sum, sum-of-squares) of one double per thread.
// Deterministic order per WG; redundant WGs execute identical sequences
// -> bitwise-identical results across all 64 WGs.
__device__ __forceinline__ void block_sum2(double v, double* sred,
                                           double& s1, double& s2) {
  double w = v * v;
  #pragma unroll
  for (int off = 32; off; off >>= 1) {
    v += __shfl_down(v, off);
    w += __shfl_down(w, off);
  }
  __syncthreads();
  if ((threadIdx.x & 63) == 0) {
    int q = threadIdx.x >> 6;
    sred[2 * q] = v; sred[2 * q + 1] = w;
  }
  __syncthreads();
  s1 = sred[0] + sred[2] + sred[4] + sred[6];
  s2 = sred[1] + sred[3] + sred[5] + sred[7];
}

// ---- fan-in-64 gathers over [w][e] partial buffers (stride 256 doubles).
// For a fixed w the 256 lanes read 2KB contiguous -> fully coalesced.
// Chunked so 16 loads are in flight while the previous chunk sums.
// Fixed accumulation order -> identical across all WGs.
__device__ __forceinline__ void gather64x2(const double* pa, const double* pb,
                                           double& ra, double& rb) {
  double a0 = 0.0, a1 = 0.0, b0 = 0.0, b1 = 0.0;
  #pragma unroll
  for (int c = 0; c < 8; ++c) {
    double ta[8], tb[8];
    #pragma unroll
    for (int k = 0; k < 8; ++k) {
      ta[k] = gld(pa + (size_t)(c * 8 + k) * 256);
      tb[k] = gld(pb + (size_t)(c * 8 + k) * 256);
    }
    #pragma unroll
    for (int k = 0; k < 8; k += 2) {
      a0 += ta[k]; a1 += ta[k + 1];
      b0 += tb[k]; b1 += tb[k + 1];
    }
  }
  ra = a0 + a1; rb = b0 + b1;
}
__device__ __forceinline__ double gather64(const double* p) {
  double a0 = 0.0, a1 = 0.0, a2 = 0.0, a3 = 0.0;
  #pragma unroll
  for (int c = 0; c < 4; ++c) {
    double t[16];
    #pragma unroll
    for (int k = 0; k < 16; ++k) t[k] = gld(p + (size_t)(c * 16 + k) * 256);
    #pragma unroll
    for (int k = 0; k < 16; k += 4) {
      a0 += t[k]; a1 += t[k + 1]; a2 += t[k + 2]; a3 += t[k + 3];
    }
  }
  return (a0 + a1) + (a2 + a3);
}

// ---------------------------------------------------------------------
// prep kernels (every launch; ~100us, fp64)
// ---------------------------------------------------------------------
__global__ void prep_zero(u32* hdr) {
  int i = blockIdx.x * 256 + threadIdx.x;
  if (i < 1024) hdr[i] = 0u;   // flags (64) + counts (256) + pad, 4KB
}

// Wg2 = Wg @ W2   [256x512];  c1 = Wg@b2 + bg
__global__ __launch_bounds__(256) void prep_mm1(const float* __restrict__ Wg,
    const float* __restrict__ W2, const float* __restrict__ b2,
    const float* __restrict__ bg, double* __restrict__ Wg2d, double* __restrict__ c1d) {
  int i = threadIdx.x, j = blockIdx.x;
  double acc = 0.0;
  for (int k = 0; k < 256; k++) acc += (double)Wg[i * 256 + k] * (double)W2[k * 512 + j];
  Wg2d[(size_t)i * 512 + j] = acc;
  if (j == 0) {
    double c = 0.0;
    for (int k = 0; k < 256; k++) c += (double)Wg[i * 256 + k] * (double)b2[k];
    c1d[i] = c + (double)bg[i];
  }
}

// Wov = Wo @ Wv  [256x256];  c2 = Wo@bv + bo
__global__ __launch_bounds__(256) void prep_mm2(const float* __restrict__ Wo,
    const float* __restrict__ Wv, const float* __restrict__ bv,
    const float* __restrict__ bo, double* __restrict__ Wovd, double* __restrict__ c2d) {
  int i = threadIdx.x, j = blockIdx.x;
  double acc = 0.0;
  for (int k = 0; k < 256; k++) acc += (double)Wo[i * 256 + k] * (double)Wv[k * 256 + j];
  Wovd[i * 256 + j] = acc;
  if (j == 0) {
    double c = 0.0;
    for (int k = 0; k < 256; k++) c += (double)Wo[i * 256 + k] * (double)bv[k];
    c2d[i] = c + (double)bo[i];
  }
}

// Awg = (I + Wov) @ Wg2  [256x512];  c3 = (I+Wov)@c1 + c2
__global__ __launch_bounds__(256) void prep_mm3(const double* __restrict__ Wg2d,
    const double* __restrict__ Wovd, const double* __restrict__ c1d,
    const double* __restrict__ c2d, double* __restrict__ Awgd, double* __restrict__ c3d) {
  int i = threadIdx.x, j = blockIdx.x;
  double acc = Wg2d[(size_t)i * 512 + j];
  for (int k = 0; k < 256; k++) acc += Wovd[i * 256 + k] * Wg2d[(size_t)k * 512 + j];
  Awgd[(size_t)i * 512 + j] = acc;
  if (j == 0) {
    double c = c1d[i] + c2d[i];
    for (int k = 0; k < 256; k++) c += Wovd[i * 256 + k] * c1d[k];
    c3d[i] = c;
  }
}

// ---------------------------------------------------------------------
// main persistent kernel: 64 WGs x 256 threads, 8192 steps, 2 barriers/step
// partial buffers pxs/hs/pgs: [w][e] fp64 (w = WG, e = element), 128KB each.
// Single-buffered: stage-A stores are gated by B2(t-1), stage-B stores by
// B1(t) -> no reader of the previous step can still be in flight.
// ---------------------------------------------------------------------
__global__ __launch_bounds__(256) void sampler_main(
    const float* __restrict__ gnn, const float* __restrict__ u,
    const float* __restrict__ W1, const float* __restrict__ b1,
    const float* __restrict__ W2, const float* __restrict__ b2,
    const float* __restrict__ Wr, const float* __restrict__ br,
    const float* __restrict__ Wf1, const float* __restrict__ bf1,
    const float* __restrict__ Wf2, const float* __restrict__ bf2,
    const float* __restrict__ ln1g, const float* __restrict__ ln1b,
    const float* __restrict__ ln2g, const float* __restrict__ ln2b,
    const double* __restrict__ Awgd, const double* __restrict__ c3d,
    double* __restrict__ pxs, double* __restrict__ hs,
    double* __restrict__ pgs, u32* __restrict__ hdr,
    float* __restrict__ out) {

  __shared__ double smg[512];        // [ m_t ; g ]
  __shared__ double sh1[8];          // local h1 slice (k-cols 8b..8b+8)
  __shared__ double sx [256];        // x = ln1(px)
  __shared__ double shh[256];        // h broadcast
  __shared__ double sf1[32];         // local f1 slice
  __shared__ double sprob[32];
  __shared__ double sred[8];
  __shared__ u32 ssamp[4];
  __shared__ u32 scnt[4];
  __shared__ int sidx;

  const int b = blockIdx.x, tid = threadIdx.x;
  u32* flags = hdr;                  // 64 contiguous u32
  u32* cnts  = hdr + 64;             // [4][64] u32: attempt-major, WG slot

  // ---- per-thread weight slices -> registers ----
  const int r1 = tid >> 5, l1 = tid & 31;     // stage A: W1 row 8b+r1
  float w1reg[16];
  #pragma unroll
  for (int k = 0; k < 16; k++) w1reg[k] = W1[(size_t)(8 * b + r1) * 512 + l1 + 32 * k];

  // K-col slices: this thread owns OUTPUT index tid, K-cols 8b..8b+8
  double areg[8]; float w2reg[8];
  #pragma unroll
  for (int k = 0; k < 8; k++) {
    areg[k]  = Awgd[(size_t)tid * 512 + 8 * b + k];
    w2reg[k] = W2  [(size_t)tid * 512 + 8 * b + k];
  }
  const int r3 = tid >> 3, l3 = tid & 7;      // stage B: rows 32b+r3
  float f1reg[32], wrreg[32];
  #pragma unroll
  for (int k = 0; k < 32; k++) {
    f1reg[k] = Wf1[(size_t)(32 * b + r3) * 256 + l3 + 8 * k];
    wrreg[k] = Wr [(size_t)(32 * b + r3) * 256 + l3 + 8 * k];
  }
  // Wf2 K-col slice: output tid, K-cols 32b..32b+32
  float f2reg[32];
  #pragma unroll
  for (int k = 0; k < 32; k++) f2reg[k] = Wf2[(size_t)tid * 2048 + 32 * b + k];

  // per-thread constants
  const double ln1gv = (double)ln1g[tid], ln1bv = (double)ln1b[tid];
  const double ln2gv = (double)ln2g[tid], ln2bv = (double)ln2b[tid];
  const double b1v  = (double)b1 [8 * b + r1];
  const double b2v  = (double)b2 [tid];
  const double c3v  =          c3d[tid];
  const double bf1v = (double)bf1[32 * b + r3];
  const double brv  = (double)br [32 * b + r3];
  const double bf2v = (double)bf2[tid];

  // initial state: m(0) = gnn row 0, g0 = 0
  smg[tid]       = (double)gnn[tid];
  smg[256 + tid] = 0.0;
  __syncthreads();

  // u(0) prefetch
  float ureg = 0.0f;
  if (tid < 128)
    ureg = u[(size_t)(tid >> 5) * 2048 + 32 * b + (tid & 31)];

  for (int t = 0; t < NSTEP; ++t) {
    // ================= stage A =================
    {
      double acc = 0.0;                         // h1 slice, rows 8b..8b+7
      #pragma unroll
      for (int k = 0; k < 16; k++) acc += (double)w1reg[k] * smg[l1 + 32 * k];
      #pragma unroll
      for (int off = 16; off; off >>= 1) acc += __shfl_down(acc, off, 32);
      if (l1 == 0) { double v = acc + b1v; sh1[r1] = (v > 0.0) ? v : 0.0; }
    }
    __syncthreads();
    {
      double pxv = 0.0, hv = 0.0;               // K-partials for px, h
      #pragma unroll
      for (int k = 0; k < 8; k++) {
        double h1k = sh1[k];
        pxv += areg[k] * h1k; hv += (double)w2reg[k] * h1k;
      }
      if (b == 0) { pxv += c3v; hv += b2v; }
      gst(&pxs[b * 256 + tid], pxv);            // coalesced 2KB store
      gst(&hs [b * 256 + tid], hv);
    }
    gbar_arrive(flags, 2 * t + 1);              // B1: px, h partials visible
    float mnf = gnn[(size_t)((t + 1) & 4095) * 256 + tid];  // m(t+1) prefetch
    gbar_wait(flags, 2 * t + 1);

    // ================= stage B =================
    double pxv, hv;
    gather64x2(pxs + tid, hs + tid, pxv, hv);   // fan-in 64, coalesced
    shh[tid] = hv;
    double xv;
    {
      double s1, s2; block_sum2(pxv, sred, s1, s2);
      double mu  = s1 * (1.0 / 256.0);
      double var = s2 * (1.0 / 256.0) - mu * mu;
      xv = (pxv - mu) * (1.0 / sqrt(var + 1e-5)) * ln1gv + ln1bv;
    }
    sx[tid]  = xv;
    smg[tid] = (double)mnf;                      // m(t+1); h1 dot done pre-B1
    __syncthreads();
    {
      double accF = 0.0, accL = 0.0;             // f1 rows + logit rows 32b+r3
      #pragma unroll
      for (int k = 0; k < 32; k++) {
        int j = l3 + 8 * k;
        accF += (double)f1reg[k] * sx[j];
        accL += (double)wrreg[k] * shh[j];
      }
      #pragma unroll
      for (int off = 4; off; off >>= 1) { accF += __shfl_down(accF, off, 8); accL += __shfl_down(accL, off, 8); }
      if (l3 == 0) {
        double fv = accF + bf1v;
        sf1[r3]   = (fv > 0.0) ? fv : 0.0;       // local f1 slice -> LDS only
        sprob[r3] = 1.0 / (1.0 + exp(-(accL + brv)));
      }
    }
    __syncthreads();
    if (tid < 128) {                             // sampling + per-WG popc store
      int a = tid >> 5;
      bool pred = ((double)ureg < sprob[tid & 31]);
      unsigned long long bal = __ballot(pred);
      int l64 = tid & 63;
      if (l64 == 0) {
        u32 mm = (u32)(bal & 0xffffffffull);
        ssamp[a] = mm; gstu(&cnts[a * 64 + b], (u32)__popc(mm));
      } else if (l64 == 32) {
        u32 mm = (u32)(bal >> 32);
        ssamp[a] = mm; gstu(&cnts[a * 64 + b], (u32)__popc(mm));
      }
    }
    {
      double pgv = 0.0;                          // pg K-partial
      #pragma unroll
      for (int k = 0; k < 32; k++) pgv += (double)f2reg[k] * sf1[k];
      if (b == 0) pgv += xv + bf2v;
      gst(&pgs[b * 256 + tid], pgv);
    }
    gbar_arrive(flags, 2 * t + 2);               // B2: pg, counts visible
    float unext = 0.0f;                          // u(t+1) prefetch (HBM)
    if (tid < 128 && t < NSTEP - 1)
      unext = u[((size_t)(t + 1) * 4 + (tid >> 5)) * 2048 + 32 * b + (tid & 31)];
    gbar_wait(flags, 2 * t + 2);

    // ================= stage C =================
    u32 cc = gldu(&cnts[tid]);                   // wave q holds attempt q's 64 slots
    double pgv = gather64(pgs + tid);
    #pragma unroll
    for (int off = 32; off; off >>= 1) cc += __shfl_down(cc, off);
    if ((tid & 63) == 0) scnt[tid >> 6] = cc;
    {
      double s1, s2; block_sum2(pgv, sred, s1, s2);   // syncs publish scnt too
      double mu  = s1 * (1.0 / 256.0);
      double var = s2 * (1.0 / 256.0) - mu * mu;
      smg[256 + tid] = (pgv - mu) * (1.0 / sqrt(var + 1e-5)) * ln2gv + ln2bv;
    }
    if (tid == 0) {
      int idx = 0;
      #pragma unroll
      for (int a = 3; a >= 0; a--) {
        u32 c = scnt[a];
        if (c == 0u || (c >= 2u && c <= 6u)) idx = a;
      }
      sidx = idx;
    }
    __syncthreads();
    if (tid < 32) {
      u32 mm = ssamp[sidx];
      gstf(&out[(size_t)t * 2048 + 32 * b + tid], ((mm >> tid) & 1u) ? 1.0f : 0.0f);
    }
    ureg = unext;
  }
}

// ---------------------------------------------------------------------
extern "C" void kernel_launch(void* const* d_in, const int* in_sizes, int n_in,
                              void* d_out, int out_size, void* d_ws, size_t ws_size,
                              hipStream_t stream) {
  const float* gnn = (const float*)d_in[0];
  const float* u   = (const float*)d_in[2];
  const float* W1  = (const float*)d_in[3];
  const float* b1  = (const float*)d_in[4];
  const float* W2  = (const float*)d_in[5];
  const float* b2  = (const float*)d_in[6];
  const float* Wr  = (const float*)d_in[7];
  const float* br  = (const float*)d_in[8];
  const float* Wg  = (const float*)d_in[9];
  const float* bg  = (const float*)d_in[10];
  const float* Wv  = (const float*)d_in[11];
  const float* bv  = (const float*)d_in[12];
  const float* Wo  = (const float*)d_in[13];
  const float* bo  = (const float*)d_in[14];
  const float* Wf1 = (const float*)d_in[15];
  const float* bf1 = (const float*)d_in[16];
  const float* Wf2 = (const float*)d_in[17];
  const float* bf2 = (const float*)d_in[18];
  const float* ln1g = (const float*)d_in[19];
  const float* ln1b = (const float*)d_in[20];
  const float* ln2g = (const float*)d_in[21];
  const float* ln2b = (const float*)d_in[22];
  float* out = (float*)d_out;

  // workspace layout:
  //   [0, 4KB)        flags (64 u32) + counts ([4][64] u32)
  //   [4KB, 132KB)    pxs  [64][256] fp64 partials
  //   [132KB, 260KB)  hs   same layout
  //   [260KB, 388KB)  pgs  same layout
  //   [388KB, ...)    prep fp64 weights
  u32* hdr = (u32*)d_ws;
  double* pxs = (double*)((char*)d_ws + 4096);   // 16384 doubles = 128KB
  double* hs  = pxs + 16384;
  double* pgs = hs + 16384;
  double* base = (double*)((char*)d_ws + 4096 + 3 * 131072);
  double* c1d   = base;            // 256
  double* c2d   = c1d + 256;       // 256
  double* c3d   = c2d + 256;       // 256
  double* Wg2d  = c3d + 256;       // 131072
  double* Wovd  = Wg2d + 131072;   // 65536
  double* Awgd  = Wovd + 65536;    // 131072

  hipLaunchKernelGGL(prep_zero, dim3(4), dim3(256), 0, stream, hdr);
  hipLaunchKernelGGL(prep_mm1, dim3(512), dim3(256), 0, stream, Wg, W2, b2, bg, Wg2d, c1d);
  hipLaunchKernelGGL(prep_mm2, dim3(256), dim3(256), 0, stream, Wo, Wv, bv, bo, Wovd, c2d);
  hipLaunchKernelGGL(prep_mm3, dim3(512), dim3(256), 0, stream, Wg2d, Wovd, c1d, c2d, Awgd, c3d);
  hipLaunchKernelGGL(sampler_main, dim3(NWG), dim3(NT), 0, stream,
                     gnn, u, W1, b1, W2, b2, Wr, br, Wf1, bf1, Wf2, bf2,
                     ln1g, ln1b, ln2g, ln2b, Awgd, c3d,
                     pxs, hs, pgs, hdr, out);
}

// Round 3
// 193853.479 us; speedup vs baseline: 2.1875x; 2.1875x over previous
//
#include <hip/hip_runtime.h>

// =====================================================================
// AutoregressiveSubsetSampler — persistent cooperative kernel, MI355X.
// Round 7: 32 WGs x 512 threads. Store/gather exchange with NO atomics,
// intra-WG LDS combine (q-split) before the store -> fan-in per thread
// is 16 (was 64), gathers chunked 8-deep (transient 32 VGPR words, no
// spill -- R6's 256-VGPR spill was the 5x regression). Flags padded to
// one 128B line per WG (R4-R6 had all flags in 2 lines -> LLC hotspot).
// 2 grid barriers/step, prefetches in the arrive->wait windows.
//
// Per step t:
//  stage A: h1 rows 16b..16b+16 -> px/h K-partials (q-split) ->
//           LDS-combine -> one 2KB store each -> arrive B1 ->
//           [m(t+1) prefetch] -> wait B1
//  stage B: split-gather px,h (16 loads/thread); fused ln1 -> x;
//           f1/logit rows 64b..64b+64 local; sampling (64-bit masks,
//           per-WG popc store); pg K-partials -> combine -> store ->
//           arrive B2 -> [u(t+1) prefetch] -> wait B2
//  stage C: split-gather pg + counts; fused ln2 -> g; pick attempt;
//           write own 64 output columns from the LOCAL mask.
// All fp64 on the logit-critical chain (binary output: ~1e-13 margin).
// Cross-WG determinism: every WG executes identical code on identical
// global inputs with fixed summation order -> bitwise-identical state.
// =====================================================================

typedef unsigned int u32;
typedef unsigned long long u64;

#define NWG   32
#define NT    512
#define NSTEP 8192

// ---- relaxed agent-scope (coherent-point) ops ----
__device__ __forceinline__ double gld(const double* p) {
  return __hip_atomic_load(p, __ATOMIC_RELAXED, __HIP_MEMORY_SCOPE_AGENT);
}
__device__ __forceinline__ void gst(double* p, double v) {
  __hip_atomic_store(p, v, __ATOMIC_RELAXED, __HIP_MEMORY_SCOPE_AGENT);
}
__device__ __forceinline__ u32 gldu(const u32* p) {
  return __hip_atomic_load(p, __ATOMIC_RELAXED, __HIP_MEMORY_SCOPE_AGENT);
}
__device__ __forceinline__ void gstu(u32* p, u32 v) {
  __hip_atomic_store(p, v, __ATOMIC_RELAXED, __HIP_MEMORY_SCOPE_AGENT);
}
__device__ __forceinline__ void gstf(float* p, float v) {
  __hip_atomic_store(p, v, __ATOMIC_RELAXED, __HIP_MEMORY_SCOPE_AGENT);
}

// ---- flag-array grid barrier, 128B-padded slots, arrive/wait split.
// __syncthreads in arrive drains each wave's vmcnt before lane 0 raises
// its flag -> all of the WG's global stores are acked first.
__device__ __forceinline__ void gbar_arrive(u32* flags, u32 e) {
  __syncthreads();
  if (threadIdx.x == 0) gstu(&flags[(u32)blockIdx.x << 5], e);
}
__device__ __forceinline__ void gbar_wait(u32* flags, u32 e) {
  if (threadIdx.x < NWG) {
    while (gldu(&flags[threadIdx.x << 5]) < e) { }
  }
  asm volatile("" ::: "memory");
  __syncthreads();
}

// fused block-wide (sum, sum-of-squares), 512 threads / 8 waves.
// Fixed order -> bitwise-identical across WGs.
__device__ __forceinline__ void block_sum2(double v, double* sred,
                                           double& s1, double& s2) {
  double w = v * v;
  #pragma unroll
  for (int off = 32; off; off >>= 1) {
    v += __shfl_down(v, off);
    w += __shfl_down(w, off);
  }
  __syncthreads();
  if ((threadIdx.x & 63) == 0) {
    int q = threadIdx.x >> 6;
    sred[2 * q] = v; sred[2 * q + 1] = w;
  }
  __syncthreads();
  s1 = ((sred[0] + sred[2]) + (sred[4] + sred[6])) +
       ((sred[8] + sred[10]) + (sred[12] + sred[14]));
  s2 = ((sred[1] + sred[3]) + (sred[5] + sred[7])) +
       ((sred[9] + sred[11]) + (sred[13] + sred[15]));
}

// ---------------------------------------------------------------------
// prep kernels (every launch; ~100us, fp64)
// ---------------------------------------------------------------------
__global__ void prep_zero(u32* hdr) {
  int i = blockIdx.x * 256 + threadIdx.x;
  if (i < 4096) hdr[i] = 0u;   // padded flags (32x32) + counts + pad, 16KB
}

// Wg2 = Wg @ W2   [256x512];  c1 = Wg@b2 + bg
__global__ __launch_bounds__(256) void prep_mm1(const float* __restrict__ Wg,
    const float* __restrict__ W2, const float* __restrict__ b2,
    const float* __restrict__ bg, double* __restrict__ Wg2d, double* __restrict__ c1d) {
  int i = threadIdx.x, j = blockIdx.x;
  double acc = 0.0;
  for (int k = 0; k < 256; k++) acc += (double)Wg[i * 256 + k] * (double)W2[k * 512 + j];
  Wg2d[(size_t)i * 512 + j] = acc;
  if (j == 0) {
    double c = 0.0;
    for (int k = 0; k < 256; k++) c += (double)Wg[i * 256 + k] * (double)b2[k];
    c1d[i] = c + (double)bg[i];
  }
}

// Wov = Wo @ Wv  [256x256];  c2 = Wo@bv + bo
__global__ __launch_bounds__(256) void prep_mm2(const float* __restrict__ Wo,
    const float* __restrict__ Wv, const float* __restrict__ bv,
    const float* __restrict__ bo, double* __restrict__ Wovd, double* __restrict__ c2d) {
  int i = threadIdx.x, j = blockIdx.x;
  double acc = 0.0;
  for (int k = 0; k < 256; k++) acc += (double)Wo[i * 256 + k] * (double)Wv[k * 256 + j];
  Wovd[i * 256 + j] = acc;
  if (j == 0) {
    double c = 0.0;
    for (int k = 0; k < 256; k++) c += (double)Wo[i * 256 + k] * (double)bv[k];
    c2d[i] = c + (double)bo[i];
  }
}

// Awg = (I + Wov) @ Wg2  [256x512];  c3 = (I+Wov)@c1 + c2
__global__ __launch_bounds__(256) void prep_mm3(const double* __restrict__ Wg2d,
    const double* __restrict__ Wovd, const double* __restrict__ c1d,
    const double* __restrict__ c2d, double* __restrict__ Awgd, double* __restrict__ c3d) {
  int i = threadIdx.x, j = blockIdx.x;
  double acc = Wg2d[(size_t)i * 512 + j];
  for (int k = 0; k < 256; k++) acc += Wovd[i * 256 + k] * Wg2d[(size_t)k * 512 + j];
  Awgd[(size_t)i * 512 + j] = acc;
  if (j == 0) {
    double c = c1d[i] + c2d[i];
    for (int k = 0; k < 256; k++) c += Wovd[i * 256 + k] * c1d[k];
    c3d[i] = c;
  }
}

// ---------------------------------------------------------------------
// main persistent kernel: 32 WGs x 512 threads, 8192 steps, 2 barriers/step
// partial buffers pxs/hs/pgs: [w][e] fp64 (w = WG, e = element), 64KB each.
// Single-buffered: WAR-safety from the 2 barriers (all reads of buffer X
// are vmcnt-drained at the arrive that precedes the next write to X).
// ---------------------------------------------------------------------
__global__ __launch_bounds__(512, 2) void sampler_main(
    const float* __restrict__ gnn, const float* __restrict__ u,
    const float* __restrict__ W1, const float* __restrict__ b1,
    const float* __restrict__ W2, const float* __restrict__ b2,
    const float* __restrict__ Wr, const float* __restrict__ br,
    const float* __restrict__ Wf1, const float* __restrict__ bf1,
    const float* __restrict__ Wf2, const float* __restrict__ bf2,
    const float* __restrict__ ln1g, const float* __restrict__ ln1b,
    const float* __restrict__ ln2g, const float* __restrict__ ln2b,
    const double* __restrict__ Awgd, const double* __restrict__ c3d,
    double* __restrict__ pxs, double* __restrict__ hs,
    double* __restrict__ pgs, u32* __restrict__ hdr,
    float* __restrict__ out) {

  __shared__ double smg[512];        // [ m_t ; g ]
  __shared__ double sh1[16];         // local h1 slice (rows 16b..16b+16)
  __shared__ double sx [256];        // x = ln1(px)
  __shared__ double shh[256];        // h broadcast
  __shared__ double sf1[64];         // local f1 slice (rows 64b..64b+64)
  __shared__ double sprob[64];
  __shared__ double sred[16];
  __shared__ double spp[2][256];     // q-combine scratch (px / gather / pg)
  __shared__ double sph[2][256];     // q-combine scratch (h)
  __shared__ u64 ssamp[4];
  __shared__ u32 scnt[4];
  __shared__ int sidx;

  const int b = blockIdx.x, tid = threadIdx.x;
  const int e = tid & 255, q = tid >> 8;      // output element / K-half
  u32* flags = hdr;                  // 32 slots, 128B stride
  u32* cnts  = hdr + 1024;           // [4][32] u32: attempt-major, WG slot

  // ---- per-thread weight slices -> registers ----
  const int r1 = tid >> 5, l1 = tid & 31;     // stage A: W1 row 16b+r1
  float w1reg[16];
  #pragma unroll
  for (int k = 0; k < 16; k++) w1reg[k] = W1[(size_t)(16 * b + r1) * 512 + l1 + 32 * k];

  // px/h K-slices: output e, K-cols 16b+8q .. +8
  double areg[8]; float w2reg[8];
  #pragma unroll
  for (int k = 0; k < 8; k++) {
    areg[k]  = Awgd[(size_t)e * 512 + 16 * b + 8 * q + k];
    w2reg[k] = W2  [(size_t)e * 512 + 16 * b + 8 * q + k];
  }
  const int r3 = tid >> 3, l3 = tid & 7;      // stage B: rows 64b+r3
  float f1reg[32], wrreg[32];
  #pragma unroll
  for (int k = 0; k < 32; k++) {
    f1reg[k] = Wf1[(size_t)(64 * b + r3) * 256 + l3 + 8 * k];
    wrreg[k] = Wr [(size_t)(64 * b + r3) * 256 + l3 + 8 * k];
  }
  // pg K-slice: output e, K-cols 64b+32q .. +32
  float f2reg[32];
  #pragma unroll
  for (int k = 0; k < 32; k++) f2reg[k] = Wf2[(size_t)e * 2048 + 64 * b + 32 * q + k];

  // per-thread constants
  const double ln1gv = (double)ln1g[e], ln1bv = (double)ln1b[e];
  const double ln2gv = (double)ln2g[e], ln2bv = (double)ln2b[e];
  const double b1v  = (double)b1 [16 * b + r1];
  const double b2v  = (double)b2 [e];
  const double c3v  =          c3d[e];
  const double bf1v = (double)bf1[64 * b + r3];
  const double brv  = (double)br [64 * b + r3];
  const double bf2v = (double)bf2[e];

  // initial state: m(0) = gnn row 0, g0 = 0
  if (tid < 256) { smg[tid] = (double)gnn[tid]; smg[256 + tid] = 0.0; }
  __syncthreads();

  // u(0) prefetch: thread tid<256: attempt a = tid>>6, row j = tid&63
  float ureg = 0.0f;
  if (tid < 256)
    ureg = u[(size_t)(tid >> 6) * 2048 + 64 * b + (tid & 63)];

  for (int t = 0; t < NSTEP; ++t) {
    // ================= stage A =================
    {
      double acc = 0.0;                         // h1 row 16b+r1
      #pragma unroll
      for (int k = 0; k < 16; k++) acc += (double)w1reg[k] * smg[l1 + 32 * k];
      #pragma unroll
      for (int off = 16; off; off >>= 1) acc += __shfl_down(acc, off, 32);
      if (l1 == 0) { double v = acc + b1v; sh1[r1] = (v > 0.0) ? v : 0.0; }
    }
    __syncthreads();
    {
      double pxv = 0.0, hv = 0.0;               // K-partials over 8 local cols
      #pragma unroll
      for (int k = 0; k < 8; k++) {
        double h1k = sh1[8 * q + k];
        pxv += areg[k] * h1k; hv += (double)w2reg[k] * h1k;
      }
      if (b == 0 && q == 0) { pxv += c3v; hv += b2v; }
      spp[q][e] = pxv; sph[q][e] = hv;
    }
    __syncthreads();
    if (tid < 256) {                            // combine q-halves, one store
      gst(&pxs[b * 256 + tid], spp[0][tid] + spp[1][tid]);
      gst(&hs [b * 256 + tid], sph[0][tid] + sph[1][tid]);
    }
    gbar_arrive(flags, 2 * t + 1);              // B1: px, h partials visible
    float mnf = 0.0f;                           // m(t+1) prefetch
    if (tid < 256) mnf = gnn[(size_t)((t + 1) & 4095) * 256 + tid];
    gbar_wait(flags, 2 * t + 1);

    // ================= stage B =================
    {
      // split gather: q half w = 16q .. 16q+15, chunks of 8 (px and h)
      const double* ps = pxs + (q << 4) * 256 + e;
      const double* hsrc = hs + (q << 4) * 256 + e;
      double a0 = 0.0, a1 = 0.0, h0 = 0.0, h1s = 0.0;
      #pragma unroll
      for (int c = 0; c < 2; ++c) {
        double ta[8], tb[8];
        #pragma unroll
        for (int k = 0; k < 8; ++k) {
          ta[k] = gld(ps   + (size_t)(c * 8 + k) * 256);
          tb[k] = gld(hsrc + (size_t)(c * 8 + k) * 256);
        }
        #pragma unroll
        for (int k = 0; k < 8; k += 2) {
          a0 += ta[k]; a1 += ta[k + 1];
          h0 += tb[k]; h1s += tb[k + 1];
        }
      }
      spp[q][e] = a0 + a1; sph[q][e] = h0 + h1s;
    }
    __syncthreads();
    double pxv = spp[0][e] + spp[1][e];         // identical in all threads/WGs
    double xv;
    {
      double s1, s2; block_sum2(pxv, sred, s1, s2);   // x2 redundancy cancels
      double mu  = s1 * (1.0 / 512.0);
      double var = s2 * (1.0 / 512.0) - mu * mu;
      xv = (pxv - mu) * (1.0 / sqrt(var + 1e-5)) * ln1gv + ln1bv;
    }
    if (q == 0) {
      sx[e]  = xv;
      shh[e] = sph[0][e] + sph[1][e];
      smg[e] = (double)mnf;                     // m(t+1); h1 done pre-B1
    }
    __syncthreads();
    {
      double accF = 0.0, accL = 0.0;            // f1 + logit rows 64b+r3
      #pragma unroll
      for (int k = 0; k < 32; k++) {
        int j = l3 + 8 * k;
        accF += (double)f1reg[k] * sx[j];
        accL += (double)wrreg[k] * shh[j];
      }
      #pragma unroll
      for (int off = 4; off; off >>= 1) { accF += __shfl_down(accF, off, 8); accL += __shfl_down(accL, off, 8); }
      if (l3 == 0) {
        double fv = accF + bf1v;
        sf1[r3]   = (fv > 0.0) ? fv : 0.0;      // local f1 slice -> LDS only
        sprob[r3] = 1.0 / (1.0 + exp(-(accL + brv)));
      }
    }
    __syncthreads();
    if (tid < 256) {                            // sampling: wave a, row j
      int a = tid >> 6, j = tid & 63;
      bool pred = ((double)ureg < sprob[j]);
      u64 bal = __ballot(pred);
      if (j == 0) {
        ssamp[a] = bal;
        gstu(&cnts[a * 32 + b], (u32)__popcll(bal));
      }
    }
    {
      double pgv = 0.0;                         // pg K-partial (32 local cols)
      #pragma unroll
      for (int k = 0; k < 32; k++) pgv += (double)f2reg[k] * sf1[32 * q + k];
      if (b == 0 && q == 0) pgv += xv + bf2v;
      spp[q][e] = pgv;
    }
    __syncthreads();
    if (tid < 256)
      gst(&pgs[b * 256 + tid], spp[0][tid] + spp[1][tid]);
    gbar_arrive(flags, 2 * t + 2);              // B2: pg, counts visible
    float unext = 0.0f;                         // u(t+1) prefetch
    if (tid < 256 && t < NSTEP - 1)
      unext = u[((size_t)(t + 1) * 4 + (tid >> 6)) * 2048 + 64 * b + (tid & 63)];
    gbar_wait(flags, 2 * t + 2);

    // ================= stage C =================
    {
      // split gather pg: q half w = 16q..16q+15, all 16 in flight
      const double* ps = pgs + (q << 4) * 256 + e;
      double ta[8], tb[8];
      #pragma unroll
      for (int k = 0; k < 8; ++k) ta[k] = gld(ps + (size_t)k * 256);
      #pragma unroll
      for (int k = 0; k < 8; ++k) tb[k] = gld(ps + (size_t)(8 + k) * 256);
      double a0 = 0.0, a1 = 0.0;
      #pragma unroll
      for (int k = 0; k < 8; k += 2) {
        a0 += ta[k] + ta[k + 1]; a1 += tb[k] + tb[k + 1];
      }
      spp[q][e] = a0 + a1;
    }
    if (tid < 128) {                            // counts: [4][32] -> scnt[4]
      u32 cc = gldu(&cnts[tid]);
      #pragma unroll
      for (int off = 16; off; off >>= 1) cc += __shfl_down(cc, off, 32);
      if ((tid & 31) == 0) scnt[tid >> 5] = cc;
    }
    __syncthreads();
    double pgv = spp[0][e] + spp[1][e];
    {
      double s1, s2; block_sum2(pgv, sred, s1, s2);
      double mu  = s1 * (1.0 / 512.0);
      double var = s2 * (1.0 / 512.0) - mu * mu;
      if (q == 0)
        smg[256 + e] = (pgv - mu) * (1.0 / sqrt(var + 1e-5)) * ln2gv + ln2bv;
    }
    if (tid == 0) {
      int idx = 0;
      #pragma unroll
      for (int a = 3; a >= 0; a--) {
        u32 c = scnt[a];
        if (c == 0u || (c >= 2u && c <= 6u)) idx = a;
      }
      sidx = idx;
    }
    __syncthreads();
    if (tid < 64) {                             // own 64 output columns
      u64 mm = ssamp[sidx];
      gstf(&out[(size_t)t * 2048 + 64 * b + tid], ((mm >> tid) & 1ull) ? 1.0f : 0.0f);
    }
    ureg = unext;
  }
}

// ---------------------------------------------------------------------
extern "C" void kernel_launch(void* const* d_in, const int* in_sizes, int n_in,
                              void* d_out, int out_size, void* d_ws, size_t ws_size,
                              hipStream_t stream) {
  const float* gnn = (const float*)d_in[0];
  const float* u   = (const float*)d_in[2];
  const float* W1  = (const float*)d_in[3];
  const float* b1  = (const float*)d_in[4];
  const float* W2  = (const float*)d_in[5];
  const float* b2  = (const float*)d_in[6];
  const float* Wr  = (const float*)d_in[7];
  const float* br  = (const float*)d_in[8];
  const float* Wg  = (const float*)d_in[9];
  const float* bg  = (const float*)d_in[10];
  const float* Wv  = (const float*)d_in[11];
  const float* bv  = (const float*)d_in[12];
  const float* Wo  = (const float*)d_in[13];
  const float* bo  = (const float*)d_in[14];
  const float* Wf1 = (const float*)d_in[15];
  const float* bf1 = (const float*)d_in[16];
  const float* Wf2 = (const float*)d_in[17];
  const float* bf2 = (const float*)d_in[18];
  const float* ln1g = (const float*)d_in[19];
  const float* ln1b = (const float*)d_in[20];
  const float* ln2g = (const float*)d_in[21];
  const float* ln2b = (const float*)d_in[22];
  float* out = (float*)d_out;

  // workspace layout:
  //   [0, 16KB)       flags (32 x 128B-padded) + counts ([4][32] u32)
  //   [16KB, 80KB)    pxs  [32][256] fp64 partials
  //   [80KB, 144KB)   hs   same layout
  //   [144KB, 208KB)  pgs  same layout
  //   [208KB, ...)    prep fp64 weights (~2.63MB)
  u32* hdr = (u32*)d_ws;
  double* pxs = (double*)((char*)d_ws + 16384);   // 8192 doubles = 64KB
  double* hs  = pxs + 8192;
  double* pgs = hs + 8192;
  double* base = (double*)((char*)d_ws + 16384 + 3 * 65536);
  double* c1d   = base;            // 256
  double* c2d   = c1d + 256;       // 256
  double* c3d   = c2d + 256;       // 256
  double* Wg2d  = c3d + 256;       // 131072
  double* Wovd  = Wg2d + 131072;   // 65536
  double* Awgd  = Wovd + 65536;    // 131072

  hipLaunchKernelGGL(prep_zero, dim3(16), dim3(256), 0, stream, hdr);
  hipLaunchKernelGGL(prep_mm1, dim3(512), dim3(256), 0, stream, Wg, W2, b2, bg, Wg2d, c1d);
  hipLaunchKernelGGL(prep_mm2, dim3(256), dim3(256), 0, stream, Wo, Wv, bv, bo, Wovd, c2d);
  hipLaunchKernelGGL(prep_mm3, dim3(512), dim3(256), 0, stream, Wg2d, Wovd, c1d, c2d, Awgd, c3d);
  hipLaunchKernelGGL(sampler_main, dim3(NWG), dim3(NT), 0, stream,
                     gnn, u, W1, b1, W2, b2, Wr, br, Wf1, bf1, Wf2, bf2,
                     ln1g, ln1b, ln2g, ln2b, Awgd, c3d,
                     pxs, hs, pgs, hdr, out);
}

// Round 4
// 109572.229 us; speedup vs baseline: 3.8702x; 1.7692x over previous
//
#include <hip/hip_runtime.h>

// =====================================================================
// AutoregressiveSubsetSampler — persistent cooperative kernel, MI355X.
// Round 8: back to the PROVEN R4 exchange (dense fp64 atomics into
// parity-double-buffered accumulators, compact flag barrier, single
// coalesced read-back). Store/gather variants (R6/R7) regressed 2-5x:
// agent-scope gather loads are pathologically slow; accumulate-at-
// memory with one coalesced load back is the right primitive here.
// Changes vs the 85.8ms R4 kernel, all strictly-decreasing costs:
//  * 32 WGs x 512 threads + LDS q-combine before the atomic ->
//    RMWs per line 2048 -> 512, total atomics halved (drain was the
//    dominant barrier term).
//  * fused single-pass LN stats (block_sum2): 2 block reductions/step
//    instead of 4.
//  * arrive/wait-split barrier, m(t+1)/u(t+1) prefetch in the window.
//  * 64-bit ballot sampling (1 popcll/attempt), parallel count fetch.
// All fp64 on the logit-critical chain (binary output: ~1e-13 margin).
// =====================================================================

typedef unsigned int u32;
typedef unsigned long long u64;

#define NWG   32
#define NT    512
#define NSTEP 8192

// ---- relaxed agent-scope ops ----
__device__ __forceinline__ double gld(const double* p) {
  return __hip_atomic_load(p, __ATOMIC_RELAXED, __HIP_MEMORY_SCOPE_AGENT);
}
__device__ __forceinline__ void gst(double* p, double v) {
  __hip_atomic_store(p, v, __ATOMIC_RELAXED, __HIP_MEMORY_SCOPE_AGENT);
}
__device__ __forceinline__ u32 gldu(const u32* p) {
  return __hip_atomic_load(p, __ATOMIC_RELAXED, __HIP_MEMORY_SCOPE_AGENT);
}
__device__ __forceinline__ void gstu(u32* p, u32 v) {
  __hip_atomic_store(p, v, __ATOMIC_RELAXED, __HIP_MEMORY_SCOPE_AGENT);
}
__device__ __forceinline__ void gstf(float* p, float v) {
  __hip_atomic_store(p, v, __ATOMIC_RELAXED, __HIP_MEMORY_SCOPE_AGENT);
}
// fp64 atomic add -> global_atomic_add_f64 (HW instr on gfx90a+/gfx950)
__device__ __forceinline__ void gadd(double* p, double v) {
  unsafeAtomicAdd(p, v);
}

// ---- compact flag-array grid barrier (R4 idiom), arrive/wait split.
// __syncthreads in arrive drains each wave's vmcnt before lane 0 raises
// its flag -> all of the WG's stores/atomics are acked first.
__device__ __forceinline__ void gbar_arrive(u32* flags, u32 e) {
  __syncthreads();
  if (threadIdx.x == 0) gstu(&flags[blockIdx.x], e);
}
__device__ __forceinline__ void gbar_wait(u32* flags, u32 e) {
  if (threadIdx.x < NWG) {
    while (gldu(&flags[threadIdx.x]) < e) { }
  }
  asm volatile("" ::: "memory");
  __syncthreads();
}

// fused block-wide (sum, sum-of-squares), 512 threads / 8 waves.
// Fixed order -> bitwise-identical across WGs (all WGs run identical
// sequences on identical global data).
__device__ __forceinline__ void block_sum2(double v, double* sred,
                                           double& s1, double& s2) {
  double w = v * v;
  #pragma unroll
  for (int off = 32; off; off >>= 1) {
    v += __shfl_down(v, off);
    w += __shfl_down(w, off);
  }
  __syncthreads();
  if ((threadIdx.x & 63) == 0) {
    int q = threadIdx.x >> 6;
    sred[2 * q] = v; sred[2 * q + 1] = w;
  }
  __syncthreads();
  s1 = ((sred[0] + sred[2]) + (sred[4] + sred[6])) +
       ((sred[8] + sred[10]) + (sred[12] + sred[14]));
  s2 = ((sred[1] + sred[3]) + (sred[5] + sred[7])) +
       ((sred[9] + sred[11]) + (sred[13] + sred[15]));
}

// ---------------------------------------------------------------------
// prep kernels (every launch; ~100us, fp64)
// ---------------------------------------------------------------------
__global__ void prep_zero(u32* hdr) {
  int i = blockIdx.x * 256 + threadIdx.x;
  if (i < 4096) hdr[i] = 0u;   // flags + counts + px/h/pg accumulators (16KB)
}

// Wg2 = Wg @ W2   [256x512];  c1 = Wg@b2 + bg
__global__ __launch_bounds__(256) void prep_mm1(const float* __restrict__ Wg,
    const float* __restrict__ W2, const float* __restrict__ b2,
    const float* __restrict__ bg, double* __restrict__ Wg2d, double* __restrict__ c1d) {
  int i = threadIdx.x, j = blockIdx.x;
  double acc = 0.0;
  for (int k = 0; k < 256; k++) acc += (double)Wg[i * 256 + k] * (double)W2[k * 512 + j];
  Wg2d[(size_t)i * 512 + j] = acc;
  if (j == 0) {
    double c = 0.0;
    for (int k = 0; k < 256; k++) c += (double)Wg[i * 256 + k] * (double)b2[k];
    c1d[i] = c + (double)bg[i];
  }
}

// Wov = Wo @ Wv  [256x256];  c2 = Wo@bv + bo
__global__ __launch_bounds__(256) void prep_mm2(const float* __restrict__ Wo,
    const float* __restrict__ Wv, const float* __restrict__ bv,
    const float* __restrict__ bo, double* __restrict__ Wovd, double* __restrict__ c2d) {
  int i = threadIdx.x, j = blockIdx.x;
  double acc = 0.0;
  for (int k = 0; k < 256; k++) acc += (double)Wo[i * 256 + k] * (double)Wv[k * 256 + j];
  Wovd[i * 256 + j] = acc;
  if (j == 0) {
    double c = 0.0;
    for (int k = 0; k < 256; k++) c += (double)Wo[i * 256 + k] * (double)bv[k];
    c2d[i] = c + (double)bo[i];
  }
}

// Awg = (I + Wov) @ Wg2  [256x512];  c3 = (I+Wov)@c1 + c2
__global__ __launch_bounds__(256) void prep_mm3(const double* __restrict__ Wg2d,
    const double* __restrict__ Wovd, const double* __restrict__ c1d,
    const double* __restrict__ c2d, double* __restrict__ Awgd, double* __restrict__ c3d) {
  int i = threadIdx.x, j = blockIdx.x;
  double acc = Wg2d[(size_t)i * 512 + j];
  for (int k = 0; k < 256; k++) acc += Wovd[i * 256 + k] * Wg2d[(size_t)k * 512 + j];
  Awgd[(size_t)i * 512 + j] = acc;
  if (j == 0) {
    double c = c1d[i] + c2d[i];
    for (int k = 0; k < 256; k++) c += Wovd[i * 256 + k] * c1d[k];
    c3d[i] = c;
  }
}

// ---------------------------------------------------------------------
// main persistent kernel: 32 WGs x 512 threads, 8192 steps, 2 barriers/step
// dense parity accumulators (R4 layout): pxbuf/hbuf/pgbuf [2][256] fp64.
// Each WG does ONE atomicAdd per element per array (after LDS q-combine).
// ---------------------------------------------------------------------
__global__ __launch_bounds__(512) void sampler_main(
    const float* __restrict__ gnn, const float* __restrict__ u,
    const float* __restrict__ W1, const float* __restrict__ b1,
    const float* __restrict__ W2, const float* __restrict__ b2,
    const float* __restrict__ Wr, const float* __restrict__ br,
    const float* __restrict__ Wf1, const float* __restrict__ bf1,
    const float* __restrict__ Wf2, const float* __restrict__ bf2,
    const float* __restrict__ ln1g, const float* __restrict__ ln1b,
    const float* __restrict__ ln2g, const float* __restrict__ ln2b,
    const double* __restrict__ Awgd, const double* __restrict__ c3d,
    double* __restrict__ pxbuf, double* __restrict__ hbuf,
    double* __restrict__ pgbuf, u32* __restrict__ hdr,
    float* __restrict__ out) {

  __shared__ double smg[512];        // [ m_t ; g ]
  __shared__ double sh1[16];         // local h1 slice (rows 16b..16b+16)
  __shared__ double sx [256];        // x = ln1(px)
  __shared__ double shh[256];        // h broadcast
  __shared__ double sf1[64];         // local f1 slice (rows 64b..64b+64)
  __shared__ double sprob[64];
  __shared__ double sred[16];
  __shared__ double spp[2][256];     // q-combine scratch (px / pg)
  __shared__ double sph[2][256];     // q-combine scratch (h)
  __shared__ u64 ssamp[4];
  __shared__ u32 scnt[4];
  __shared__ int sidx;

  const int b = blockIdx.x, tid = threadIdx.x;
  const int e = tid & 255, q = tid >> 8;      // output element / K-half
  u32* flags  = hdr;                 // 32 contiguous u32 (1 line)
  u32* counts = hdr + 96;            // [2][4] u32, stride 32 (padded)

  // ---- per-thread weight slices -> registers (R7 layout, 128 VGPR) ----
  const int r1 = tid >> 5, l1 = tid & 31;     // stage A: W1 row 16b+r1
  float w1reg[16];
  #pragma unroll
  for (int k = 0; k < 16; k++) w1reg[k] = W1[(size_t)(16 * b + r1) * 512 + l1 + 32 * k];

  // px/h K-slices: output e, K-cols 16b+8q .. +8
  double areg[8]; float w2reg[8];
  #pragma unroll
  for (int k = 0; k < 8; k++) {
    areg[k]  = Awgd[(size_t)e * 512 + 16 * b + 8 * q + k];
    w2reg[k] = W2  [(size_t)e * 512 + 16 * b + 8 * q + k];
  }
  const int r3 = tid >> 3, l3 = tid & 7;      // stage B: rows 64b+r3
  float f1reg[32], wrreg[32];
  #pragma unroll
  for (int k = 0; k < 32; k++) {
    f1reg[k] = Wf1[(size_t)(64 * b + r3) * 256 + l3 + 8 * k];
    wrreg[k] = Wr [(size_t)(64 * b + r3) * 256 + l3 + 8 * k];
  }
  // pg K-slice: output e, K-cols 64b+32q .. +32
  float f2reg[32];
  #pragma unroll
  for (int k = 0; k < 32; k++) f2reg[k] = Wf2[(size_t)e * 2048 + 64 * b + 32 * q + k];

  // per-thread constants
  const double ln1gv = (double)ln1g[e], ln1bv = (double)ln1b[e];
  const double ln2gv = (double)ln2g[e], ln2bv = (double)ln2b[e];
  const double b1v  = (double)b1 [16 * b + r1];
  const double b2v  = (double)b2 [e];
  const double c3v  =          c3d[e];
  const double bf1v = (double)bf1[64 * b + r3];
  const double brv  = (double)br [64 * b + r3];
  const double bf2v = (double)bf2[e];

  // initial state: m(0) = gnn row 0, g0 = 0
  if (tid < 256) { smg[tid] = (double)gnn[tid]; smg[256 + tid] = 0.0; }
  __syncthreads();

  // u(0) prefetch: attempt a = tid>>6, local row j = tid&63
  float ureg = 0.0f;
  if (tid < 256)
    ureg = u[(size_t)(tid >> 6) * 2048 + 64 * b + (tid & 63)];

  for (int t = 0; t < NSTEP; ++t) {
    const int p = t & 1;
    double* pxp = pxbuf + p * 256;
    double* hp_ = hbuf  + p * 256;
    double* pgp = pgbuf + p * 256;
    u32*   cntp = counts + p * 4 * 32;

    // ================= stage A =================
    {
      double acc = 0.0;                         // h1 row 16b+r1
      #pragma unroll
      for (int k = 0; k < 16; k++) acc += (double)w1reg[k] * smg[l1 + 32 * k];
      #pragma unroll
      for (int off = 16; off; off >>= 1) acc += __shfl_down(acc, off, 32);
      if (l1 == 0) { double v = acc + b1v; sh1[r1] = (v > 0.0) ? v : 0.0; }
    }
    __syncthreads();
    {
      double pxv = 0.0, hv = 0.0;               // K-partials over 8 local cols
      #pragma unroll
      for (int k = 0; k < 8; k++) {
        double h1k = sh1[8 * q + k];
        pxv += areg[k] * h1k; hv += (double)w2reg[k] * h1k;
      }
      if (b == 0 && q == 0) { pxv += c3v; hv += b2v; }
      spp[q][e] = pxv; sph[q][e] = hv;
    }
    __syncthreads();
    if (tid < 256) {                            // q-combine -> ONE atomic each
      gadd(&pxp[tid], spp[0][tid] + spp[1][tid]);
      gadd(&hp_[tid], sph[0][tid] + sph[1][tid]);
    }
    gbar_arrive(flags, 2 * t + 1);              // B1: px, h complete
    float mnf = 0.0f;                           // m(t+1) prefetch
    if (tid < 256) mnf = gnn[(size_t)((t + 1) & 4095) * 256 + tid];
    gbar_wait(flags, 2 * t + 1);

    // ================= stage B =================
    double pxv = gld(&pxp[e]);                  // one coalesced load each
    double hv  = gld(&hp_[e]);
    double xv;
    {
      double s1, s2; block_sum2(pxv, sred, s1, s2);  // 2x redundancy cancels
      double mu  = s1 * (1.0 / 512.0);
      double var = s2 * (1.0 / 512.0) - mu * mu;
      xv = (pxv - mu) * (1.0 / sqrt(var + 1e-5)) * ln1gv + ln1bv;
    }
    if (q == 0) {
      sx[e]  = xv;
      shh[e] = hv;
      smg[e] = (double)mnf;                     // m(t+1); h1 dot done pre-B1
    }
    __syncthreads();
    {
      double accF = 0.0, accL = 0.0;            // f1 + logit rows 64b+r3
      #pragma unroll
      for (int k = 0; k < 32; k++) {
        int j = l3 + 8 * k;
        accF += (double)f1reg[k] * sx[j];
        accL += (double)wrreg[k] * shh[j];
      }
      #pragma unroll
      for (int off = 4; off; off >>= 1) { accF += __shfl_down(accF, off, 8); accL += __shfl_down(accL, off, 8); }
      if (l3 == 0) {
        double fv = accF + bf1v;
        sf1[r3]   = (fv > 0.0) ? fv : 0.0;      // local f1 slice -> LDS only
        sprob[r3] = 1.0 / (1.0 + exp(-(accL + brv)));
      }
    }
    __syncthreads();
    if (tid < 256) {                            // sampling: wave a, row 64b+j
      int a = tid >> 6, j = tid & 63;
      bool pred = ((double)ureg < sprob[j]);
      u64 bal = __ballot(pred);
      if (j == 0) {
        ssamp[a] = bal;
        atomicAdd(&cntp[a * 32], (u32)__popcll(bal));
      }
    }
    {
      double pgv = 0.0;                         // pg K-partial (32 local cols)
      #pragma unroll
      for (int k = 0; k < 32; k++) pgv += (double)f2reg[k] * sf1[32 * q + k];
      if (b == 0 && q == 0) pgv += xv + bf2v;
      spp[q][e] = pgv;
    }
    __syncthreads();
    if (tid < 256)
      gadd(&pgp[tid], spp[0][tid] + spp[1][tid]);
    if (b == 1) {                               // zero next-parity accums
      if (tid < 256) {
        gst(&pxbuf[(1 - p) * 256 + tid], 0.0);
        gst(&hbuf [(1 - p) * 256 + tid], 0.0);
        gst(&pgbuf[(1 - p) * 256 + tid], 0.0);
      }
      if (tid < 4) gstu(&counts[(1 - p) * 4 * 32 + tid * 32], 0u);
    }
    gbar_arrive(flags, 2 * t + 2);              // B2: pg, counts complete
    float unext = 0.0f;                         // u(t+1) prefetch (HBM)
    if (tid < 256 && t < NSTEP - 1)
      unext = u[((size_t)(t + 1) * 4 + (tid >> 6)) * 2048 + 64 * b + (tid & 63)];
    gbar_wait(flags, 2 * t + 2);

    // ================= stage C =================
    double pgv = gld(&pgp[e]);
    if (tid < 4) scnt[tid] = gldu(&cntp[tid * 32]);   // parallel count fetch
    {
      double s1, s2; block_sum2(pgv, sred, s1, s2);   // syncs publish scnt
      double mu  = s1 * (1.0 / 512.0);
      double var = s2 * (1.0 / 512.0) - mu * mu;
      if (q == 0)
        smg[256 + e] = (pgv - mu) * (1.0 / sqrt(var + 1e-5)) * ln2gv + ln2bv;
    }
    if (tid == 0) {
      int idx = 0;
      #pragma unroll
      for (int a = 3; a >= 0; a--) {
        u32 c = scnt[a];
        if (c == 0u || (c >= 2u && c <= 6u)) idx = a;
      }
      sidx = idx;
    }
    __syncthreads();
    if (tid < 64) {                             // own 64 output columns
      u64 mm = ssamp[sidx];
      gstf(&out[(size_t)t * 2048 + 64 * b + tid], ((mm >> tid) & 1ull) ? 1.0f : 0.0f);
    }
    ureg = unext;
  }
}

// ---------------------------------------------------------------------
extern "C" void kernel_launch(void* const* d_in, const int* in_sizes, int n_in,
                              void* d_out, int out_size, void* d_ws, size_t ws_size,
                              hipStream_t stream) {
  const float* gnn = (const float*)d_in[0];
  const float* u   = (const float*)d_in[2];
  const float* W1  = (const float*)d_in[3];
  const float* b1  = (const float*)d_in[4];
  const float* W2  = (const float*)d_in[5];
  const float* b2  = (const float*)d_in[6];
  const float* Wr  = (const float*)d_in[7];
  const float* br  = (const float*)d_in[8];
  const float* Wg  = (const float*)d_in[9];
  const float* bg  = (const float*)d_in[10];
  const float* Wv  = (const float*)d_in[11];
  const float* bv  = (const float*)d_in[12];
  const float* Wo  = (const float*)d_in[13];
  const float* bo  = (const float*)d_in[14];
  const float* Wf1 = (const float*)d_in[15];
  const float* bf1 = (const float*)d_in[16];
  const float* Wf2 = (const float*)d_in[17];
  const float* bf2 = (const float*)d_in[18];
  const float* ln1g = (const float*)d_in[19];
  const float* ln1b = (const float*)d_in[20];
  const float* ln2g = (const float*)d_in[21];
  const float* ln2b = (const float*)d_in[22];
  float* out = (float*)d_out;

  // workspace: [0,16KB) = flags/counts (4KB) + px/h/pg parity accumulators
  u32* hdr = (u32*)d_ws;
  double* pxbuf = (double*)((char*)d_ws + 4096);   // [2][256]
  double* hbuf  = pxbuf + 512;                     // [2][256]
  double* pgbuf = hbuf  + 512;                     // [2][256]
  double* base  = (double*)((char*)d_ws + 16384);
  double* c1d   = base;            // 256
  double* c2d   = c1d + 256;       // 256
  double* c3d   = c2d + 256;       // 256
  double* Wg2d  = c3d + 256;       // 131072
  double* Wovd  = Wg2d + 131072;   // 65536
  double* Awgd  = Wovd + 65536;    // 131072

  hipLaunchKernelGGL(prep_zero, dim3(16), dim3(256), 0, stream, hdr);
  hipLaunchKernelGGL(prep_mm1, dim3(512), dim3(256), 0, stream, Wg, W2, b2, bg, Wg2d, c1d);
  hipLaunchKernelGGL(prep_mm2, dim3(256), dim3(256), 0, stream, Wo, Wv, bv, bo, Wovd, c2d);
  hipLaunchKernelGGL(prep_mm3, dim3(512), dim3(256), 0, stream, Wg2d, Wovd, c1d, c2d, Awgd, c3d);
  hipLaunchKernelGGL(sampler_main, dim3(NWG), dim3(NT), 0, stream,
                     gnn, u, W1, b1, W2, b2, Wr, br, Wf1, bf1, Wf2, bf2,
                     ln1g, ln1b, ln2g, ln2b, Awgd, c3d,
                     pxbuf, hbuf, pgbuf, hdr, out);
}

// Round 5
// 57771.228 us; speedup vs baseline: 7.3404x; 1.8967x over previous
//
#include <hip/hip_runtime.h>

// =====================================================================
// AutoregressiveSubsetSampler — MI355X. Round 9: ALGORITHMIC SPLIT.
// Key fact (from the reference): the sampled rows NEVER feed back into
// the recurrent state. g(t+1) = F(m(t), g(t)) only. So:
//   Phase 1 (serial, 64WGx256T, R4's PROVEN exchange): state recurrence
//     only — h1 -> px -> ln1 -> f1 -> pg -> ln2. Logs h1(t) (512 fp64)
//     per step into the UPPER HALF of d_out (33.5MB of the 67MB buffer).
//     B1 carries ONE atomic array (px) instead of two (px,h); logits,
//     sampling, counts, u-prefetch and output writes all removed.
//   Phase 2A (1024 WGs, 8 steps each, embarrassingly parallel):
//     h = W2@h1+b2, logits = Wr@h+br (8-step register reuse), sigmoid,
//     compare vs u, counts (packed-u64 shuffle reduce), pick attempt,
//     emit 2048-bit row masks (2MB in ws).
//   Phase 2B: expand masks -> fp32 rows (overwrites the h1 log region
//     only after 2A has consumed it; kernel-boundary ordered).
// All fp64 on the logit-critical chain (binary output: ~1e-13 margin).
// =====================================================================

typedef unsigned int u32;
typedef unsigned long long u64;

#define NWG   64
#define NT    256
#define NSTEP 8192

// ---- relaxed agent-scope ops ----
__device__ __forceinline__ double gld(const double* p) {
  return __hip_atomic_load(p, __ATOMIC_RELAXED, __HIP_MEMORY_SCOPE_AGENT);
}
__device__ __forceinline__ void gst(double* p, double v) {
  __hip_atomic_store(p, v, __ATOMIC_RELAXED, __HIP_MEMORY_SCOPE_AGENT);
}
__device__ __forceinline__ u32 gldu(const u32* p) {
  return __hip_atomic_load(p, __ATOMIC_RELAXED, __HIP_MEMORY_SCOPE_AGENT);
}
__device__ __forceinline__ void gstu(u32* p, u32 v) {
  __hip_atomic_store(p, v, __ATOMIC_RELAXED, __HIP_MEMORY_SCOPE_AGENT);
}
// fp64 atomic add -> global_atomic_add_f64 (HW instr on gfx950)
__device__ __forceinline__ void gadd(double* p, double v) {
  unsafeAtomicAdd(p, v);
}

// ---- R4-proven compact flag barrier (64 u32), arrive/wait split ----
__device__ __forceinline__ void gbar_arrive(u32* flags, u32 e) {
  __syncthreads();
  if (threadIdx.x == 0) gstu(&flags[blockIdx.x], e);
}
__device__ __forceinline__ void gbar_wait(u32* flags, u32 e) {
  if (threadIdx.x < 64) {
    while (gldu(&flags[threadIdx.x]) < e) { }
  }
  asm volatile("" ::: "memory");
  __syncthreads();
}

// fused block-wide (sum, sum-of-squares), 256 threads / 4 waves.
// Fixed order -> bitwise-identical across WGs.
__device__ __forceinline__ void block_sum2(double v, double* sred,
                                           double& s1, double& s2) {
  double w = v * v;
  #pragma unroll
  for (int off = 32; off; off >>= 1) {
    v += __shfl_down(v, off);
    w += __shfl_down(w, off);
  }
  __syncthreads();
  if ((threadIdx.x & 63) == 0) {
    int q = threadIdx.x >> 6;
    sred[2 * q] = v; sred[2 * q + 1] = w;
  }
  __syncthreads();
  s1 = (sred[0] + sred[2]) + (sred[4] + sred[6]);
  s2 = (sred[1] + sred[3]) + (sred[5] + sred[7]);
}

// ---------------------------------------------------------------------
// prep kernels (every launch; ~100us, fp64)
// ---------------------------------------------------------------------
__global__ void prep_zero(u32* hdr) {
  int i = blockIdx.x * 256 + threadIdx.x;
  if (i < 4096) hdr[i] = 0u;   // flags + px/pg parity accumulators (16KB)
}

// Wg2 = Wg @ W2   [256x512];  c1 = Wg@b2 + bg
__global__ __launch_bounds__(256) void prep_mm1(const float* __restrict__ Wg,
    const float* __restrict__ W2, const float* __restrict__ b2,
    const float* __restrict__ bg, double* __restrict__ Wg2d, double* __restrict__ c1d) {
  int i = threadIdx.x, j = blockIdx.x;
  double acc = 0.0;
  for (int k = 0; k < 256; k++) acc += (double)Wg[i * 256 + k] * (double)W2[k * 512 + j];
  Wg2d[(size_t)i * 512 + j] = acc;
  if (j == 0) {
    double c = 0.0;
    for (int k = 0; k < 256; k++) c += (double)Wg[i * 256 + k] * (double)b2[k];
    c1d[i] = c + (double)bg[i];
  }
}

// Wov = Wo @ Wv  [256x256];  c2 = Wo@bv + bo
__global__ __launch_bounds__(256) void prep_mm2(const float* __restrict__ Wo,
    const float* __restrict__ Wv, const float* __restrict__ bv,
    const float* __restrict__ bo, double* __restrict__ Wovd, double* __restrict__ c2d) {
  int i = threadIdx.x, j = blockIdx.x;
  double acc = 0.0;
  for (int k = 0; k < 256; k++) acc += (double)Wo[i * 256 + k] * (double)Wv[k * 256 + j];
  Wovd[i * 256 + j] = acc;
  if (j == 0) {
    double c = 0.0;
    for (int k = 0; k < 256; k++) c += (double)Wo[i * 256 + k] * (double)bv[k];
    c2d[i] = c + (double)bo[i];
  }
}

// Awg = (I + Wov) @ Wg2  [256x512];  c3 = (I+Wov)@c1 + c2
__global__ __launch_bounds__(256) void prep_mm3(const double* __restrict__ Wg2d,
    const double* __restrict__ Wovd, const double* __restrict__ c1d,
    const double* __restrict__ c2d, double* __restrict__ Awgd, double* __restrict__ c3d) {
  int i = threadIdx.x, j = blockIdx.x;
  double acc = Wg2d[(size_t)i * 512 + j];
  for (int k = 0; k < 256; k++) acc += Wovd[i * 256 + k] * Wg2d[(size_t)k * 512 + j];
  Awgd[(size_t)i * 512 + j] = acc;
  if (j == 0) {
    double c = c1d[i] + c2d[i];
    for (int k = 0; k < 256; k++) c += Wovd[i * 256 + k] * c1d[k];
    c3d[i] = c;
  }
}

// ---------------------------------------------------------------------
// PHASE 1: state recurrence. 64 WGs x 256 threads, 2 barriers/step.
// R4-exact exchange idioms; ONE fp64 atomic array per barrier.
// Writes h1log[t][512] (plain coalesced stores, upper half of d_out).
// ---------------------------------------------------------------------
__global__ __launch_bounds__(256) void sampler_state(
    const float* __restrict__ gnn,
    const float* __restrict__ W1, const float* __restrict__ b1,
    const float* __restrict__ Wf1, const float* __restrict__ bf1,
    const float* __restrict__ Wf2, const float* __restrict__ bf2,
    const float* __restrict__ ln1g, const float* __restrict__ ln1b,
    const float* __restrict__ ln2g, const float* __restrict__ ln2b,
    const double* __restrict__ Awgd, const double* __restrict__ c3d,
    double* __restrict__ pxbuf, double* __restrict__ pgbuf,
    u32* __restrict__ hdr, double* __restrict__ h1log) {

  __shared__ double smg[512];        // [ m_t ; g ]
  __shared__ double sh1[8];          // local h1 slice (rows 8b..8b+8)
  __shared__ double sx [256];        // x = ln1(px)
  __shared__ double sf1[32];         // local f1 slice (rows 32b..32b+32)
  __shared__ double sred[8];

  const int b = blockIdx.x, tid = threadIdx.x;
  u32* flags = hdr;                  // 64 contiguous u32 (R4-proven)

  // ---- per-thread weight slices -> registers ----
  const int r1 = tid >> 5, l1 = tid & 31;     // stage A: W1 row 8b+r1
  float w1reg[16];
  #pragma unroll
  for (int k = 0; k < 16; k++) w1reg[k] = W1[(size_t)(8 * b + r1) * 512 + l1 + 32 * k];

  double areg[8];                    // px K-slice: output tid, K-cols 8b..8b+8
  #pragma unroll
  for (int k = 0; k < 8; k++) areg[k] = Awgd[(size_t)tid * 512 + 8 * b + k];

  const int r3 = tid >> 3, l3 = tid & 7;      // stage B: f1 rows 32b+r3
  float f1reg[32];
  #pragma unroll
  for (int k = 0; k < 32; k++) f1reg[k] = Wf1[(size_t)(32 * b + r3) * 256 + l3 + 8 * k];
  float f2reg[32];                   // pg K-slice: output tid, K-cols 32b..32b+32
  #pragma unroll
  for (int k = 0; k < 32; k++) f2reg[k] = Wf2[(size_t)tid * 2048 + 32 * b + k];

  // per-thread constants
  const double ln1gv = (double)ln1g[tid], ln1bv = (double)ln1b[tid];
  const double ln2gv = (double)ln2g[tid], ln2bv = (double)ln2b[tid];
  const double b1v  = (double)b1 [8 * b + r1];
  const double c3v  =          c3d[tid];
  const double bf1v = (double)bf1[32 * b + r3];
  const double bf2v = (double)bf2[tid];

  // initial state: m(0) = gnn row 0, g0 = 0
  smg[tid]       = (double)gnn[tid];
  smg[256 + tid] = 0.0;
  __syncthreads();

  for (int t = 0; t < NSTEP; ++t) {
    const int p = t & 1;
    double* pxp = pxbuf + p * 256;
    double* pgp = pgbuf + p * 256;

    // ================= stage A =================
    {
      double acc = 0.0;                         // h1 row 8b+r1
      #pragma unroll
      for (int k = 0; k < 16; k++) acc += (double)w1reg[k] * smg[l1 + 32 * k];
      #pragma unroll
      for (int off = 16; off; off >>= 1) acc += __shfl_down(acc, off, 32);
      if (l1 == 0) {
        double v = acc + b1v; v = (v > 0.0) ? v : 0.0;
        sh1[r1] = v;
        h1log[(size_t)t * 512 + 8 * b + r1] = v;   // log for phase 2
      }
    }
    __syncthreads();
    {
      double pxv = 0.0;                         // px K-partial (8 local cols)
      #pragma unroll
      for (int k = 0; k < 8; k++) pxv += areg[k] * sh1[k];
      if (b == 0) pxv += c3v;
      gadd(&pxp[tid], pxv);
    }
    gbar_arrive(flags, 2 * t + 1);              // B1: px complete
    float mnf = gnn[(size_t)((t + 1) & 4095) * 256 + tid];  // m(t+1) prefetch
    gbar_wait(flags, 2 * t + 1);

    // ================= stage B =================
    double pxv = gld(&pxp[tid]);
    double xv;
    {
      double s1, s2; block_sum2(pxv, sred, s1, s2);
      double mu  = s1 * (1.0 / 256.0);
      double var = s2 * (1.0 / 256.0) - mu * mu;
      xv = (pxv - mu) * (1.0 / sqrt(var + 1e-5)) * ln1gv + ln1bv;
    }
    sx[tid]  = xv;
    smg[tid] = (double)mnf;                     // m(t+1); h1 dot done pre-B1
    __syncthreads();
    {
      double accF = 0.0;                        // f1 row 32b+r3
      #pragma unroll
      for (int k = 0; k < 32; k++) accF += (double)f1reg[k] * sx[l3 + 8 * k];
      #pragma unroll
      for (int off = 4; off; off >>= 1) accF += __shfl_down(accF, off, 8);
      if (l3 == 0) {
        double fv = accF + bf1v;
        sf1[r3] = (fv > 0.0) ? fv : 0.0;        // local f1 slice -> LDS only
      }
    }
    __syncthreads();
    {
      double pgv = 0.0;                         // pg K-partial (32 local cols)
      #pragma unroll
      for (int k = 0; k < 32; k++) pgv += (double)f2reg[k] * sf1[k];
      if (b == 0) pgv += xv + bf2v;
      gadd(&pgp[tid], pgv);
    }
    if (b == 1) {                               // zero next-parity accums
      gst(&pxbuf[(1 - p) * 256 + tid], 0.0);
      gst(&pgbuf[(1 - p) * 256 + tid], 0.0);
    }
    gbar_arrive(flags, 2 * t + 2);              // B2: pg complete
    gbar_wait(flags, 2 * t + 2);

    // ================= stage C =================
    double pgv = gld(&pgp[tid]);
    {
      double s1, s2; block_sum2(pgv, sred, s1, s2);
      double mu  = s1 * (1.0 / 256.0);
      double var = s2 * (1.0 / 256.0) - mu * mu;
      smg[256 + tid] = (pgv - mu) * (1.0 / sqrt(var + 1e-5)) * ln2gv + ln2bv;
    }
    __syncthreads();                            // publish g before next stage A
  }
}

// ---------------------------------------------------------------------
// PHASE 2A: batched logits + sampling. 1024 WGs x 256 threads,
// 8 steps per WG (8x register reuse of Wr/W2 streams).
// Emits 2048-bit row masks: mask[t][32] u64.
// ---------------------------------------------------------------------
__global__ __launch_bounds__(256) void sampler_logits(
    const double* __restrict__ h1log, const float* __restrict__ u,
    const float* __restrict__ W2, const float* __restrict__ b2,
    const float* __restrict__ Wr, const float* __restrict__ br,
    u64* __restrict__ mask) {

  __shared__ double sh1[8 * 512];    // 8 steps' h1 (32KB)
  __shared__ double shh[8 * 256];    // 8 steps' h   (16KB)
  __shared__ u64 scw[4][8];          // per-wave packed counts
  __shared__ int ssel[8];

  const int tid = threadIdx.x;
  const int bt = blockIdx.x * 8;     // first step of this WG
  const int wv = tid >> 6, lane = tid & 63;

  // load 8 steps' h1 (coalesced)
  #pragma unroll
  for (int i = 0; i < 16; i++)
    sh1[tid + 256 * i] = h1log[(size_t)bt * 512 + tid + 256 * i];
  __syncthreads();

  // h[s][tid] = b2 + W2[tid,:] @ h1[s]   (W2 row streamed once, 8x reuse)
  {
    double acc8[8];
    double bb = (double)b2[tid];
    #pragma unroll
    for (int s = 0; s < 8; s++) acc8[s] = bb;
    const float* w2row = W2 + (size_t)tid * 512;
    for (int k = 0; k < 512; k++) {
      double w = (double)w2row[k];
      #pragma unroll
      for (int s = 0; s < 8; s++) acc8[s] += w * sh1[s * 512 + k];
    }
    #pragma unroll
    for (int s = 0; s < 8; s++) shh[s * 256 + tid] = acc8[s];
  }
  __syncthreads();

  // logits rows r = tid + 256*i ; sample 4 attempts per (s, row)
  u32 samp[8];
  #pragma unroll
  for (int s = 0; s < 8; s++) samp[s] = 0u;

  for (int i = 0; i < 8; i++) {
    int r = tid + 256 * i;
    double acc[8];
    #pragma unroll
    for (int s = 0; s < 8; s++) acc[s] = 0.0;
    const float* wrow = Wr + (size_t)r * 256;
    for (int k = 0; k < 256; k++) {
      double w = (double)wrow[k];
      #pragma unroll
      for (int s = 0; s < 8; s++) acc[s] += w * shh[s * 256 + k];
    }
    double bb = (double)br[r];
    #pragma unroll
    for (int s = 0; s < 8; s++) {
      double prob = 1.0 / (1.0 + exp(-(acc[s] + bb)));
      #pragma unroll
      for (int a = 0; a < 4; a++) {
        float uv = u[((size_t)(bt + s) * 4 + a) * 2048 + r];
        if ((double)uv < prob) samp[s] |= (1u << (a * 8 + i));
      }
    }
  }

  // counts: pack 4 attempt-counts into u64 (16-bit fields), reduce
  #pragma unroll
  for (int s = 0; s < 8; s++) {
    u64 v = 0;
    #pragma unroll
    for (int a = 0; a < 4; a++)
      v |= (u64)__popc((samp[s] >> (8 * a)) & 0xFF) << (16 * a);
    #pragma unroll
    for (int off = 32; off; off >>= 1) v += __shfl_down(v, off);
    if (lane == 0) scw[wv][s] = v;
  }
  __syncthreads();
  if (tid < 8) {
    u64 tot = ((scw[0][tid] + scw[1][tid]) + (scw[2][tid] + scw[3][tid]));
    int idx = 0;
    #pragma unroll
    for (int a = 3; a >= 0; a--) {
      u32 c = (u32)((tot >> (16 * a)) & 0xFFFFu);
      if (c == 0u || (c >= 2u && c <= 6u)) idx = a;
    }
    ssel[tid] = idx;
  }
  __syncthreads();

  // emit row masks via ballot: word (4i + wv) covers rows 256i + 64wv ..
  #pragma unroll
  for (int s = 0; s < 8; s++) {
    int sel = ssel[s];
    #pragma unroll
    for (int i = 0; i < 8; i++) {
      u64 bits = __ballot((samp[s] >> (sel * 8 + i)) & 1u);
      if (lane == 0) mask[(size_t)(bt + s) * 32 + 4 * i + wv] = bits;
    }
  }
}

// ---------------------------------------------------------------------
// PHASE 2B: expand masks -> fp32 rows (overwrites h1log region; safe,
// runs strictly after 2A).
// ---------------------------------------------------------------------
__global__ __launch_bounds__(256) void sampler_expand(
    const u64* __restrict__ mask, float* __restrict__ out) {
  const int t = blockIdx.x, tid = threadIdx.x;
  const int wv = tid >> 6, lane = tid & 63;
  #pragma unroll
  for (int i = 0; i < 8; i++) {
    u64 w = mask[(size_t)t * 32 + 4 * i + wv];
    out[(size_t)t * 2048 + 256 * i + tid] = ((w >> lane) & 1ull) ? 1.0f : 0.0f;
  }
}

// ---------------------------------------------------------------------
extern "C" void kernel_launch(void* const* d_in, const int* in_sizes, int n_in,
                              void* d_out, int out_size, void* d_ws, size_t ws_size,
                              hipStream_t stream) {
  const float* gnn = (const float*)d_in[0];
  const float* u   = (const float*)d_in[2];
  const float* W1  = (const float*)d_in[3];
  const float* b1  = (const float*)d_in[4];
  const float* W2  = (const float*)d_in[5];
  const float* b2  = (const float*)d_in[6];
  const float* Wr  = (const float*)d_in[7];
  const float* br  = (const float*)d_in[8];
  const float* Wg  = (const float*)d_in[9];
  const float* bg  = (const float*)d_in[10];
  const float* Wv  = (const float*)d_in[11];
  const float* bv  = (const float*)d_in[12];
  const float* Wo  = (const float*)d_in[13];
  const float* bo  = (const float*)d_in[14];
  const float* Wf1 = (const float*)d_in[15];
  const float* bf1 = (const float*)d_in[16];
  const float* Wf2 = (const float*)d_in[17];
  const float* bf2 = (const float*)d_in[18];
  const float* ln1g = (const float*)d_in[19];
  const float* ln1b = (const float*)d_in[20];
  const float* ln2g = (const float*)d_in[21];
  const float* ln2b = (const float*)d_in[22];
  float* out = (float*)d_out;

  // h1 log lives in the upper half of d_out (67.1MB total, log = 33.5MB)
  double* h1log = (double*)((char*)d_out + 33554432);

  // workspace layout:
  //   [0, 4KB)        flags (64 u32)
  //   [4KB, 8KB)      pxbuf [2][256] fp64
  //   [8KB, 12KB)     pgbuf [2][256] fp64
  //   [16KB, 2MB+16KB) mask [8192][32] u64 (2MB)
  //   [4MB, ...)      prep fp64 weights (~2.63MB)
  u32* hdr = (u32*)d_ws;
  double* pxbuf = (double*)((char*)d_ws + 4096);
  double* pgbuf = (double*)((char*)d_ws + 8192);
  u64*    mask  = (u64*)((char*)d_ws + 16384);
  double* base  = (double*)((char*)d_ws + (4u << 20));
  double* c1d   = base;            // 256
  double* c2d   = c1d + 256;       // 256
  double* c3d   = c2d + 256;       // 256
  double* Wg2d  = c3d + 256;       // 131072
  double* Wovd  = Wg2d + 131072;   // 65536
  double* Awgd  = Wovd + 65536;    // 131072

  hipLaunchKernelGGL(prep_zero, dim3(16), dim3(256), 0, stream, hdr);
  hipLaunchKernelGGL(prep_mm1, dim3(512), dim3(256), 0, stream, Wg, W2, b2, bg, Wg2d, c1d);
  hipLaunchKernelGGL(prep_mm2, dim3(256), dim3(256), 0, stream, Wo, Wv, bv, bo, Wovd, c2d);
  hipLaunchKernelGGL(prep_mm3, dim3(512), dim3(256), 0, stream, Wg2d, Wovd, c1d, c2d, Awgd, c3d);
  hipLaunchKernelGGL(sampler_state, dim3(NWG), dim3(NT), 0, stream,
                     gnn, W1, b1, Wf1, bf1, Wf2, bf2,
                     ln1g, ln1b, ln2g, ln2b, Awgd, c3d,
                     pxbuf, pgbuf, hdr, h1log);
  hipLaunchKernelGGL(sampler_logits, dim3(1024), dim3(256), 0, stream,
                     h1log, u, W2, b2, Wr, br, mask);
  hipLaunchKernelGGL(sampler_expand, dim3(8192), dim3(256), 0, stream,
                     mask, out);
}